// Round 4
// baseline (399.878 us; speedup 1.0000x reference)
//
#include <hip/hip_runtime.h>
#include <cstddef>

#define HID 128
#define LN_EPS 1e-5f
#define GROWS 8

__device__ __forceinline__ float wave_sum(float v) {
#pragma unroll
  for (int o = 32; o > 0; o >>= 1) v += __shfl_xor(v, o, 64);
  return v;
}

extern "C" __global__ void k_zero(int* __restrict__ p, int n) {
  int i = blockIdx.x * blockDim.x + threadIdx.x;
  if (i < n) p[i] = 0;
}

extern "C" __global__ void k_deg(const int* __restrict__ dst, int* __restrict__ deg, int E) {
  int i = blockIdx.x * blockDim.x + threadIdx.x;
  if (i < E) atomicAdd(&deg[dst[i]], 1);
}

extern "C" __global__ void k_dinv(const int* __restrict__ deg, float* __restrict__ dinv, int N) {
  int i = blockIdx.x * blockDim.x + threadIdx.x;
  if (i < N) dinv[i] = rsqrtf((float)deg[i] + 1.0f);
}

extern "C" __global__ void k_scan1(const int* __restrict__ in, int* __restrict__ exc,
                                   int* __restrict__ bsum, int n) {
  __shared__ int sh[256];
  int tid = threadIdx.x;
  int i = blockIdx.x * 256 + tid;
  int v = (i < n) ? in[i] : 0;
  sh[tid] = v;
  __syncthreads();
  for (int o = 1; o < 256; o <<= 1) {
    int t = (tid >= o) ? sh[tid - o] : 0;
    __syncthreads();
    sh[tid] += t;
    __syncthreads();
  }
  if (i < n) exc[i] = sh[tid] - v;
  if (tid == 255) bsum[blockIdx.x] = sh[255];
}

extern "C" __global__ void k_scan2(const int* __restrict__ bsum, int* __restrict__ bbase, int nb) {
  __shared__ int sh[256];
  int tid = threadIdx.x;
  int v = (tid < nb) ? bsum[tid] : 0;
  sh[tid] = v;
  __syncthreads();
  for (int o = 1; o < 256; o <<= 1) {
    int t = (tid >= o) ? sh[tid - o] : 0;
    __syncthreads();
    sh[tid] += t;
    __syncthreads();
  }
  if (tid < nb) bbase[tid] = sh[tid] - v;
}

extern "C" __global__ void k_scan3(const int* __restrict__ exc, const int* __restrict__ bbase,
                                   int* __restrict__ roff, int* __restrict__ cursor, int N, int E) {
  int i = blockIdx.x * blockDim.x + threadIdx.x;
  if (i < N) {
    int o = exc[i] + bbase[i >> 8];
    roff[i] = o;
    cursor[i] = o;
  } else if (i == N) {
    roff[N] = E;
  }
}

extern "C" __global__ void k_fill(const int* __restrict__ src, const int* __restrict__ dst,
                                  int* __restrict__ cursor, int* __restrict__ csrc, int E) {
  int i = blockIdx.x * blockDim.x + threadIdx.x;
  if (i < E) {
    int pos = atomicAdd(&cursor[dst[i]], 1);
    csrc[pos] = src[i];
  }
}

// g[r][c] = dinv[r] * sum_k x[r][k] * W[k][c]
extern "C" __global__ __launch_bounds__(256) void k_gemm(
    const float* __restrict__ x, const float* __restrict__ W,
    const float* __restrict__ dinv, float* __restrict__ g, int N) {
  __shared__ float Wl[HID * HID];       // 64 KiB
  __shared__ float xl[4][GROWS * HID];  // 16 KiB
  int tid = threadIdx.x;
#pragma unroll
  for (int i = 0; i < (HID * HID / 4) / 256; ++i)
    ((float4*)Wl)[tid + 256 * i] = ((const float4*)W)[tid + 256 * i];
  __syncthreads();
  int wid = tid >> 6, lane = tid & 63;
  float* xw = xl[wid];
  int nchunks = (N + GROWS - 1) / GROWS;
  int gw = blockIdx.x * 4 + wid;
  int nw = gridDim.x * 4;
  for (int chunk = gw; chunk < nchunks; chunk += nw) {
    int r0 = chunk * GROWS;
    int nr = min(GROWS, N - r0);
    const float4* xs = (const float4*)(x + (size_t)r0 * HID);
    float4* xd = (float4*)xw;
    if (nr == GROWS) {
#pragma unroll
      for (int i = 0; i < 4; ++i) xd[lane + 64 * i] = xs[lane + 64 * i];
    } else {
      for (int i = lane; i < nr * (HID / 4); i += 64) xd[i] = xs[i];
    }
    float2 acc[GROWS];
#pragma unroll
    for (int r = 0; r < GROWS; ++r) acc[r] = make_float2(0.f, 0.f);
    for (int k = 0; k < HID; k += 4) {
      float2 w0 = *(const float2*)&Wl[(k + 0) * HID + 2 * lane];
      float2 w1 = *(const float2*)&Wl[(k + 1) * HID + 2 * lane];
      float2 w2 = *(const float2*)&Wl[(k + 2) * HID + 2 * lane];
      float2 w3 = *(const float2*)&Wl[(k + 3) * HID + 2 * lane];
#pragma unroll
      for (int r = 0; r < GROWS; ++r) {
        float4 xq = *(const float4*)&xw[r * HID + k];
        acc[r].x = fmaf(xq.w, w3.x, fmaf(xq.z, w2.x, fmaf(xq.y, w1.x, fmaf(xq.x, w0.x, acc[r].x))));
        acc[r].y = fmaf(xq.w, w3.y, fmaf(xq.z, w2.y, fmaf(xq.y, w1.y, fmaf(xq.x, w0.y, acc[r].y))));
      }
    }
#pragma unroll
    for (int r = 0; r < GROWS; ++r) {
      if (r < nr) {
        float dv = dinv[r0 + r];
        float2 o = make_float2(acc[r].x * dv, acc[r].y * dv);
        *(float2*)(g + (size_t)(r0 + r) * HID + 2 * lane) = o;
      }
    }
  }
}

// CSR gather: h[v] = dinv[v]*(g[v] + sum_{e->v} g[src_e]) + b
extern "C" __global__ __launch_bounds__(256) void k_agg(
    const float* __restrict__ g, const int* __restrict__ roff, const int* __restrict__ csrc,
    const float* __restrict__ dinv, const float* __restrict__ bias,
    const float* __restrict__ gamma, const float* __restrict__ beta,
    float* __restrict__ out0, int N, int last) {
  int w = (int)((blockIdx.x * blockDim.x + threadIdx.x) >> 6);
  int lane = threadIdx.x & 63;
  if (w >= N) return;
  int e = roff[w], e1 = roff[w + 1];
  float2 acc = *(const float2*)(g + (size_t)w * HID + 2 * lane);
  for (; e + 4 <= e1; e += 4) {
    int s0 = csrc[e], s1 = csrc[e + 1], s2 = csrc[e + 2], s3 = csrc[e + 3];
    float2 a0 = *(const float2*)(g + (size_t)s0 * HID + 2 * lane);
    float2 a1 = *(const float2*)(g + (size_t)s1 * HID + 2 * lane);
    float2 a2 = *(const float2*)(g + (size_t)s2 * HID + 2 * lane);
    float2 a3 = *(const float2*)(g + (size_t)s3 * HID + 2 * lane);
    acc.x += (a0.x + a1.x) + (a2.x + a3.x);
    acc.y += (a0.y + a1.y) + (a2.y + a3.y);
  }
  for (; e < e1; ++e) {
    int s = csrc[e];
    float2 a = *(const float2*)(g + (size_t)s * HID + 2 * lane);
    acc.x += a.x;
    acc.y += a.y;
  }
  float dv = dinv[w];
  float2 bb = *(const float2*)(bias + 2 * lane);
  float hx = fmaf(acc.x, dv, bb.x);
  float hy = fmaf(acc.y, dv, bb.y);
  if (last) {
    *(float2*)(out0 + (size_t)w * HID + 2 * lane) = make_float2(hx, hy);
  } else {
    float rx = fmaxf(hx, 0.f), ry = fmaxf(hy, 0.f);
    float mu = wave_sum(rx + ry) * (1.f / HID);
    float dx = rx - mu, dy = ry - mu;
    float var = wave_sum(dx * dx + dy * dy) * (1.f / HID);
    float sc = rsqrtf(var + LN_EPS);
    float2 ga = *(const float2*)(gamma + 2 * lane);
    float2 be = *(const float2*)(beta + 2 * lane);
    *(float2*)(out0 + (size_t)w * HID + 2 * lane) =
        make_float2(fmaf(dx * sc, ga.x, be.x), fmaf(dy * sc, ga.y, be.y));
  }
}

extern "C" __global__ void k_copy(const float* __restrict__ in, float* __restrict__ out, int n4) {
  int i = blockIdx.x * blockDim.x + threadIdx.x;
  if (i < n4) ((float4*)out)[i] = ((const float4*)in)[i];
}

// scatter fallback: acc[dst_e] += g[src_e]  (one wave per edge, float2 per lane)
extern "C" __global__ void k_scatter(const float* __restrict__ g, const int* __restrict__ src,
                                     const int* __restrict__ dst, float* __restrict__ acc, int E) {
  int e = (int)((blockIdx.x * blockDim.x + threadIdx.x) >> 6);
  int lane = threadIdx.x & 63;
  if (e >= E) return;
  int s = src[e], d = dst[e];
  float2 v = *(const float2*)(g + (size_t)s * HID + 2 * lane);
  float* p = acc + (size_t)d * HID + 2 * lane;
  atomicAdd(p, v.x);
  atomicAdd(p + 1, v.y);
}

// finalize for scatter path: in-place h = dinv*acc + b ; then epilogue
extern "C" __global__ __launch_bounds__(256) void k_fin(
    float* __restrict__ a, const float* __restrict__ dinv, const float* __restrict__ bias,
    const float* __restrict__ gamma, const float* __restrict__ beta, int N, int last) {
  int w = (int)((blockIdx.x * blockDim.x + threadIdx.x) >> 6);
  int lane = threadIdx.x & 63;
  if (w >= N) return;
  float2 acc = *(const float2*)(a + (size_t)w * HID + 2 * lane);
  float dv = dinv[w];
  float2 bb = *(const float2*)(bias + 2 * lane);
  float hx = fmaf(acc.x, dv, bb.x);
  float hy = fmaf(acc.y, dv, bb.y);
  if (last) {
    *(float2*)(a + (size_t)w * HID + 2 * lane) = make_float2(hx, hy);
  } else {
    float rx = fmaxf(hx, 0.f), ry = fmaxf(hy, 0.f);
    float mu = wave_sum(rx + ry) * (1.f / HID);
    float dx = rx - mu, dy = ry - mu;
    float var = wave_sum(dx * dx + dy * dy) * (1.f / HID);
    float sc = rsqrtf(var + LN_EPS);
    float2 ga = *(const float2*)(gamma + 2 * lane);
    float2 be = *(const float2*)(beta + 2 * lane);
    *(float2*)(a + (size_t)w * HID + 2 * lane) =
        make_float2(fmaf(dx * sc, ga.x, be.x), fmaf(dy * sc, ga.y, be.y));
  }
}

extern "C" __global__ void k_relu(const float* __restrict__ in, float* __restrict__ out, int n4) {
  int i = blockIdx.x * blockDim.x + threadIdx.x;
  if (i < n4) {
    float4 v = ((const float4*)in)[i];
    v.x = fmaxf(v.x, 0.f);
    v.y = fmaxf(v.y, 0.f);
    v.z = fmaxf(v.z, 0.f);
    v.w = fmaxf(v.w, 0.f);
    ((float4*)out)[i] = v;
  }
}

extern "C" void kernel_launch(void* const* d_in, const int* in_sizes, int n_in,
                              void* d_out, int out_size, void* d_ws, size_t ws_size,
                              hipStream_t stream) {
  const float* x0 = (const float*)d_in[0];
  const int* ei = (const int*)d_in[1];
  int N = in_sizes[0] / HID;
  int E = in_sizes[1] / 2;

  // Input layout: lists may arrive as separate leaves (n_in=14) or as one
  // concatenated array per list (n_in=6). Detect via in_sizes[2].
  const float* W[3];
  const float* b[3];
  const float* gm[3];
  const float* bt[3];
  if (n_in >= 14 && in_sizes[2] == HID * HID) {
    for (int l = 0; l < 3; ++l) {
      W[l] = (const float*)d_in[2 + l];
      b[l] = (const float*)d_in[5 + l];
      gm[l] = (const float*)d_in[8 + l];
      bt[l] = (const float*)d_in[11 + l];
    }
  } else if (n_in >= 6) {
    const float* Wc = (const float*)d_in[2];
    const float* bc = (const float*)d_in[3];
    const float* gc = (const float*)d_in[4];
    const float* tc = (const float*)d_in[5];
    for (int l = 0; l < 3; ++l) {
      W[l] = Wc + (size_t)l * HID * HID;
      b[l] = bc + (size_t)l * HID;
      gm[l] = gc + (size_t)l * HID;
      bt[l] = tc + (size_t)l * HID;
    }
  } else {
    return;
  }
  const int* src = ei;
  const int* dst = ei + E;

  float* OUT0 = (float*)d_out;
  float* OUT1 = OUT0 + (size_t)N * HID;

  // CSR-build transients live in OUT1 (dead space until layer-0 GEMM writes it)
  int* deg = (int*)OUT1;
  int* exc = deg + N;
  int* cursor = exc + N;
  int* bsum = cursor + N;
  int* bbase = bsum + 256;

  // persistent workspace: dinv always; roff+csrc only if ws_size permits
  auto align256 = [](size_t bytes) { return (bytes + 255) & ~(size_t)255; };
  size_t need_scatter = align256((size_t)N * 4);
  size_t need_csr = need_scatter + align256((size_t)(N + 1) * 4) + (size_t)E * 4;
  if (ws_size < need_scatter) return;  // cannot run safely
  bool use_csr = (ws_size >= need_csr);

  char* wp = (char*)d_ws;
  float* dinv = (float*)wp;
  wp += align256((size_t)N * 4);
  int* roff = nullptr;
  int* csrc = nullptr;
  if (use_csr) {
    roff = (int*)wp;
    wp += align256((size_t)(N + 1) * 4);
    csrc = (int*)wp;
  }

  // degree + dinv
  k_zero<<<(N + 255) / 256, 256, 0, stream>>>(deg, N);
  k_deg<<<(E + 255) / 256, 256, 0, stream>>>(dst, deg, E);
  k_dinv<<<(N + 255) / 256, 256, 0, stream>>>(deg, dinv, N);

  int nb = (N + 255) / 256;
  if (use_csr) {
    k_scan1<<<nb, 256, 0, stream>>>(deg, exc, bsum, N);
    k_scan2<<<1, 256, 0, stream>>>(bsum, bbase, nb);
    k_scan3<<<(N + 256) / 256, 256, 0, stream>>>(exc, bbase, roff, cursor, N, E);
    k_fill<<<(E + 255) / 256, 256, 0, stream>>>(src, dst, cursor, csrc, E);
  }

  int aggBlocks = (N * 64 + 255) / 256;
  int scatBlocks = (E * 64 + 255) / 256;
  int n4 = N * HID / 4;
  for (int l = 0; l < 3; ++l) {
    const float* xin = (l == 0) ? x0 : OUT0;
    int last = (l == 2);
    k_gemm<<<512, 256, 0, stream>>>(xin, W[l], dinv, OUT1, N);
    if (use_csr) {
      k_agg<<<aggBlocks, 256, 0, stream>>>(OUT1, roff, csrc, dinv, b[l], gm[l], bt[l],
                                           OUT0, N, last);
    } else {
      k_copy<<<(n4 + 255) / 256, 256, 0, stream>>>(OUT1, OUT0, n4);
      k_scatter<<<scatBlocks, 256, 0, stream>>>(OUT1, src, dst, OUT0, E);
      k_fin<<<aggBlocks, 256, 0, stream>>>(OUT0, dinv, b[l], gm[l], bt[l], N, last);
    }
  }
  // OUT1 = relu(OUT0)
  k_relu<<<(n4 + 255) / 256, 256, 0, stream>>>(OUT0, OUT1, n4);
}

// Round 5
// 312.534 us; speedup vs baseline: 1.2795x; 1.2795x over previous
//
#include <hip/hip_runtime.h>
#include <cstddef>

#define HID 128
#define LN_EPS 1e-5f
#define GROWS 8

typedef unsigned int uint32;

__device__ __forceinline__ float wave_sum(float v) {
#pragma unroll
  for (int o = 32; o > 0; o >>= 1) v += __shfl_xor(v, o, 64);
  return v;
}

// RNE-pack two fp32 into 2xbf16 (x -> low16, y -> high16)
__device__ __forceinline__ uint32 pack_bf2(float x, float y) {
  uint32 ux = __float_as_uint(x);
  uint32 uy = __float_as_uint(y);
  ux += 0x7fffu + ((ux >> 16) & 1u);
  uy += 0x7fffu + ((uy >> 16) & 1u);
  return (ux >> 16) | (uy & 0xffff0000u);
}

extern "C" __global__ void k_zero(int* __restrict__ p, int n) {
  int i = blockIdx.x * blockDim.x + threadIdx.x;
  if (i < n) p[i] = 0;
}

extern "C" __global__ void k_deg(const int* __restrict__ dst, int* __restrict__ deg, int E) {
  int i = blockIdx.x * blockDim.x + threadIdx.x;
  if (i < E) atomicAdd(&deg[dst[i]], 1);
}

extern "C" __global__ void k_dinv(const int* __restrict__ deg, float* __restrict__ dinv, int N) {
  int i = blockIdx.x * blockDim.x + threadIdx.x;
  if (i < N) dinv[i] = rsqrtf((float)deg[i] + 1.0f);
}

extern "C" __global__ void k_scan1(const int* __restrict__ in, int* __restrict__ exc,
                                   int* __restrict__ bsum, int n) {
  __shared__ int sh[256];
  int tid = threadIdx.x;
  int i = blockIdx.x * 256 + tid;
  int v = (i < n) ? in[i] : 0;
  sh[tid] = v;
  __syncthreads();
  for (int o = 1; o < 256; o <<= 1) {
    int t = (tid >= o) ? sh[tid - o] : 0;
    __syncthreads();
    sh[tid] += t;
    __syncthreads();
  }
  if (i < n) exc[i] = sh[tid] - v;
  if (tid == 255) bsum[blockIdx.x] = sh[255];
}

extern "C" __global__ void k_scan2(const int* __restrict__ bsum, int* __restrict__ bbase, int nb) {
  __shared__ int sh[256];
  int tid = threadIdx.x;
  int v = (tid < nb) ? bsum[tid] : 0;
  sh[tid] = v;
  __syncthreads();
  for (int o = 1; o < 256; o <<= 1) {
    int t = (tid >= o) ? sh[tid - o] : 0;
    __syncthreads();
    sh[tid] += t;
    __syncthreads();
  }
  if (tid < nb) bbase[tid] = sh[tid] - v;
}

extern "C" __global__ void k_scan3(const int* __restrict__ exc, const int* __restrict__ bbase,
                                   int* __restrict__ roff, int* __restrict__ cursor, int N, int E) {
  int i = blockIdx.x * blockDim.x + threadIdx.x;
  if (i < N) {
    int o = exc[i] + bbase[i >> 8];
    roff[i] = o;
    cursor[i] = o;
  } else if (i == N) {
    roff[N] = E;
  }
}

extern "C" __global__ void k_fill(const int* __restrict__ src, const int* __restrict__ dst,
                                  int* __restrict__ cursor, int* __restrict__ csrc, int E) {
  int i = blockIdx.x * blockDim.x + threadIdx.x;
  if (i < E) {
    int pos = atomicAdd(&cursor[dst[i]], 1);
    csrc[pos] = src[i];
  }
}

// g[r][c] = dinv[r]*sum_k x[r][k]*W[k][c], packed bf16 output (uint32 per lane)
extern "C" __global__ __launch_bounds__(256) void k_gemm_bf(
    const float* __restrict__ x, const float* __restrict__ W,
    const float* __restrict__ dinv, uint32* __restrict__ gb, int N) {
  __shared__ float Wl[HID * HID];       // 64 KiB
  __shared__ float xl[4][GROWS * HID];  // 16 KiB
  int tid = threadIdx.x;
#pragma unroll
  for (int i = 0; i < (HID * HID / 4) / 256; ++i)
    ((float4*)Wl)[tid + 256 * i] = ((const float4*)W)[tid + 256 * i];
  __syncthreads();
  int wid = tid >> 6, lane = tid & 63;
  float* xw = xl[wid];
  int nchunks = (N + GROWS - 1) / GROWS;
  int gw = blockIdx.x * 4 + wid;
  int nw = gridDim.x * 4;
  for (int chunk = gw; chunk < nchunks; chunk += nw) {
    int r0 = chunk * GROWS;
    int nr = min(GROWS, N - r0);
    const float4* xs = (const float4*)(x + (size_t)r0 * HID);
    float4* xd = (float4*)xw;
    if (nr == GROWS) {
#pragma unroll
      for (int i = 0; i < 4; ++i) xd[lane + 64 * i] = xs[lane + 64 * i];
    } else {
      for (int i = lane; i < nr * (HID / 4); i += 64) xd[i] = xs[i];
    }
    float2 acc[GROWS];
#pragma unroll
    for (int r = 0; r < GROWS; ++r) acc[r] = make_float2(0.f, 0.f);
    for (int k = 0; k < HID; k += 4) {
      float2 w0 = *(const float2*)&Wl[(k + 0) * HID + 2 * lane];
      float2 w1 = *(const float2*)&Wl[(k + 1) * HID + 2 * lane];
      float2 w2 = *(const float2*)&Wl[(k + 2) * HID + 2 * lane];
      float2 w3 = *(const float2*)&Wl[(k + 3) * HID + 2 * lane];
#pragma unroll
      for (int r = 0; r < GROWS; ++r) {
        float4 xq = *(const float4*)&xw[r * HID + k];
        acc[r].x = fmaf(xq.w, w3.x, fmaf(xq.z, w2.x, fmaf(xq.y, w1.x, fmaf(xq.x, w0.x, acc[r].x))));
        acc[r].y = fmaf(xq.w, w3.y, fmaf(xq.z, w2.y, fmaf(xq.y, w1.y, fmaf(xq.x, w0.y, acc[r].y))));
      }
    }
#pragma unroll
    for (int r = 0; r < GROWS; ++r) {
      if (r < nr) {
        float dv = dinv[r0 + r];
        gb[(size_t)(r0 + r) * 64 + lane] = pack_bf2(acc[r].x * dv, acc[r].y * dv);
      }
    }
  }
}

// h[v] = dinv[v]*(g[v] + sum g[src]) + b from bf16-packed g.
// mode 0: out0 = LN(relu(h)); mode 1: out0 = h; mode 3: out0 = h, out1 = relu(h)
extern "C" __global__ __launch_bounds__(256) void k_agg_bf(
    const uint32* __restrict__ gb, const int* __restrict__ roff, const int* __restrict__ csrc,
    const float* __restrict__ dinv, const float* __restrict__ bias,
    const float* __restrict__ gamma, const float* __restrict__ beta,
    float* __restrict__ out0, float* __restrict__ out1, int N, int mode) {
  int w = (int)((blockIdx.x * blockDim.x + threadIdx.x) >> 6);
  int lane = threadIdx.x & 63;
  if (w >= N) return;
  uint32 us = gb[(size_t)w * 64 + lane];
  int e = roff[w], e1 = roff[w + 1];
  float ax = __uint_as_float(us << 16);
  float ay = __uint_as_float(us & 0xffff0000u);
  for (; e < e1; e += 8) {
#pragma unroll
    for (int i = 0; i < 8; ++i) {
      int idx = e + i;
      int cl = (idx < e1) ? idx : (e1 - 1);
      int s = csrc[cl];
      uint32 u = gb[(size_t)s * 64 + lane];
      float m = (idx < e1) ? 1.f : 0.f;
      ax = fmaf(m, __uint_as_float(u << 16), ax);
      ay = fmaf(m, __uint_as_float(u & 0xffff0000u), ay);
    }
  }
  float dv = dinv[w];
  float2 bb = *(const float2*)(bias + 2 * lane);
  float hx = fmaf(ax, dv, bb.x);
  float hy = fmaf(ay, dv, bb.y);
  if (mode) {
    *(float2*)(out0 + (size_t)w * HID + 2 * lane) = make_float2(hx, hy);
    if (mode & 2)
      *(float2*)(out1 + (size_t)w * HID + 2 * lane) =
          make_float2(fmaxf(hx, 0.f), fmaxf(hy, 0.f));
  } else {
    float rx = fmaxf(hx, 0.f), ry = fmaxf(hy, 0.f);
    float mu = wave_sum(rx + ry) * (1.f / HID);
    float dx = rx - mu, dy = ry - mu;
    float var = wave_sum(dx * dx + dy * dy) * (1.f / HID);
    float sc = rsqrtf(var + LN_EPS);
    float2 ga = *(const float2*)(gamma + 2 * lane);
    float2 be = *(const float2*)(beta + 2 * lane);
    *(float2*)(out0 + (size_t)w * HID + 2 * lane) =
        make_float2(fmaf(dx * sc, ga.x, be.x), fmaf(dy * sc, ga.y, be.y));
  }
}

// ---- fp32 scatter fallback path (only used if workspace is tiny) ----
extern "C" __global__ __launch_bounds__(256) void k_gemm(
    const float* __restrict__ x, const float* __restrict__ W,
    const float* __restrict__ dinv, float* __restrict__ g, int N) {
  __shared__ float Wl[HID * HID];
  __shared__ float xl[4][GROWS * HID];
  int tid = threadIdx.x;
#pragma unroll
  for (int i = 0; i < (HID * HID / 4) / 256; ++i)
    ((float4*)Wl)[tid + 256 * i] = ((const float4*)W)[tid + 256 * i];
  __syncthreads();
  int wid = tid >> 6, lane = tid & 63;
  float* xw = xl[wid];
  int nchunks = (N + GROWS - 1) / GROWS;
  int gw = blockIdx.x * 4 + wid;
  int nw = gridDim.x * 4;
  for (int chunk = gw; chunk < nchunks; chunk += nw) {
    int r0 = chunk * GROWS;
    int nr = min(GROWS, N - r0);
    const float4* xs = (const float4*)(x + (size_t)r0 * HID);
    float4* xd = (float4*)xw;
    if (nr == GROWS) {
#pragma unroll
      for (int i = 0; i < 4; ++i) xd[lane + 64 * i] = xs[lane + 64 * i];
    } else {
      for (int i = lane; i < nr * (HID / 4); i += 64) xd[i] = xs[i];
    }
    float2 acc[GROWS];
#pragma unroll
    for (int r = 0; r < GROWS; ++r) acc[r] = make_float2(0.f, 0.f);
    for (int k = 0; k < HID; k += 4) {
      float2 w0 = *(const float2*)&Wl[(k + 0) * HID + 2 * lane];
      float2 w1 = *(const float2*)&Wl[(k + 1) * HID + 2 * lane];
      float2 w2 = *(const float2*)&Wl[(k + 2) * HID + 2 * lane];
      float2 w3 = *(const float2*)&Wl[(k + 3) * HID + 2 * lane];
#pragma unroll
      for (int r = 0; r < GROWS; ++r) {
        float4 xq = *(const float4*)&xw[r * HID + k];
        acc[r].x = fmaf(xq.w, w3.x, fmaf(xq.z, w2.x, fmaf(xq.y, w1.x, fmaf(xq.x, w0.x, acc[r].x))));
        acc[r].y = fmaf(xq.w, w3.y, fmaf(xq.z, w2.y, fmaf(xq.y, w1.y, fmaf(xq.x, w0.y, acc[r].y))));
      }
    }
#pragma unroll
    for (int r = 0; r < GROWS; ++r) {
      if (r < nr) {
        float dv = dinv[r0 + r];
        *(float2*)(g + (size_t)(r0 + r) * HID + 2 * lane) =
            make_float2(acc[r].x * dv, acc[r].y * dv);
      }
    }
  }
}

extern "C" __global__ void k_copy(const float* __restrict__ in, float* __restrict__ out, int n4) {
  int i = blockIdx.x * blockDim.x + threadIdx.x;
  if (i < n4) ((float4*)out)[i] = ((const float4*)in)[i];
}

extern "C" __global__ void k_scatter(const float* __restrict__ g, const int* __restrict__ src,
                                     const int* __restrict__ dst, float* __restrict__ acc, int E) {
  int e = (int)((blockIdx.x * blockDim.x + threadIdx.x) >> 6);
  int lane = threadIdx.x & 63;
  if (e >= E) return;
  int s = src[e], d = dst[e];
  float2 v = *(const float2*)(g + (size_t)s * HID + 2 * lane);
  float* p = acc + (size_t)d * HID + 2 * lane;
  atomicAdd(p, v.x);
  atomicAdd(p + 1, v.y);
}

extern "C" __global__ __launch_bounds__(256) void k_fin(
    float* __restrict__ a, const float* __restrict__ dinv, const float* __restrict__ bias,
    const float* __restrict__ gamma, const float* __restrict__ beta, int N, int last) {
  int w = (int)((blockIdx.x * blockDim.x + threadIdx.x) >> 6);
  int lane = threadIdx.x & 63;
  if (w >= N) return;
  float2 acc = *(const float2*)(a + (size_t)w * HID + 2 * lane);
  float dv = dinv[w];
  float2 bb = *(const float2*)(bias + 2 * lane);
  float hx = fmaf(acc.x, dv, bb.x);
  float hy = fmaf(acc.y, dv, bb.y);
  if (last) {
    *(float2*)(a + (size_t)w * HID + 2 * lane) = make_float2(hx, hy);
  } else {
    float rx = fmaxf(hx, 0.f), ry = fmaxf(hy, 0.f);
    float mu = wave_sum(rx + ry) * (1.f / HID);
    float dx = rx - mu, dy = ry - mu;
    float var = wave_sum(dx * dx + dy * dy) * (1.f / HID);
    float sc = rsqrtf(var + LN_EPS);
    float2 ga = *(const float2*)(gamma + 2 * lane);
    float2 be = *(const float2*)(beta + 2 * lane);
    *(float2*)(a + (size_t)w * HID + 2 * lane) =
        make_float2(fmaf(dx * sc, ga.x, be.x), fmaf(dy * sc, ga.y, be.y));
  }
}

extern "C" __global__ void k_relu(const float* __restrict__ in, float* __restrict__ out, int n4) {
  int i = blockIdx.x * blockDim.x + threadIdx.x;
  if (i < n4) {
    float4 v = ((const float4*)in)[i];
    v.x = fmaxf(v.x, 0.f);
    v.y = fmaxf(v.y, 0.f);
    v.z = fmaxf(v.z, 0.f);
    v.w = fmaxf(v.w, 0.f);
    ((float4*)out)[i] = v;
  }
}

extern "C" void kernel_launch(void* const* d_in, const int* in_sizes, int n_in,
                              void* d_out, int out_size, void* d_ws, size_t ws_size,
                              hipStream_t stream) {
  const float* x0 = (const float*)d_in[0];
  const int* ei = (const int*)d_in[1];
  int N = in_sizes[0] / HID;
  int E = in_sizes[1] / 2;

  const float* W[3];
  const float* b[3];
  const float* gm[3];
  const float* bt[3];
  if (n_in >= 14 && in_sizes[2] == HID * HID) {
    for (int l = 0; l < 3; ++l) {
      W[l] = (const float*)d_in[2 + l];
      b[l] = (const float*)d_in[5 + l];
      gm[l] = (const float*)d_in[8 + l];
      bt[l] = (const float*)d_in[11 + l];
    }
  } else if (n_in >= 6) {
    const float* Wc = (const float*)d_in[2];
    const float* bc = (const float*)d_in[3];
    const float* gc = (const float*)d_in[4];
    const float* tc = (const float*)d_in[5];
    for (int l = 0; l < 3; ++l) {
      W[l] = Wc + (size_t)l * HID * HID;
      b[l] = bc + (size_t)l * HID;
      gm[l] = gc + (size_t)l * HID;
      bt[l] = tc + (size_t)l * HID;
    }
  } else {
    return;
  }
  const int* src = ei;
  const int* dst = ei + E;

  float* OUT0 = (float*)d_out;
  float* OUT1 = OUT0 + (size_t)N * HID;

  // CSR-build transients live in OUT1 (dead until first use of gbf/last-agg)
  int* deg = (int*)OUT1;
  int* exc = deg + N;
  int* cursor = exc + N;
  int* bsum = cursor + N;
  int* bbase = bsum + 256;

  auto align256 = [](size_t bytes) { return (bytes + 255) & ~(size_t)255; };
  size_t need_scatter = align256((size_t)N * 4);
  size_t need_csr = need_scatter + align256((size_t)(N + 1) * 4) + align256((size_t)E * 4);
  size_t need_full = need_csr + (size_t)N * 256;  // + bf16 g (N*64 uints)
  if (ws_size < need_scatter) return;
  bool use_csr = (ws_size >= need_csr);
  bool g_in_ws = (ws_size >= need_full);

  char* wp = (char*)d_ws;
  float* dinv = (float*)wp;
  wp += align256((size_t)N * 4);
  int* roff = nullptr;
  int* csrc = nullptr;
  uint32* gbf = nullptr;
  if (use_csr) {
    roff = (int*)wp;
    wp += align256((size_t)(N + 1) * 4);
    csrc = (int*)wp;
    wp += align256((size_t)E * 4);
    gbf = g_in_ws ? (uint32*)wp : (uint32*)OUT1;  // bf16 g: 12.8 MB
  }

  k_zero<<<(N + 255) / 256, 256, 0, stream>>>(deg, N);
  k_deg<<<(E + 255) / 256, 256, 0, stream>>>(dst, deg, E);
  k_dinv<<<(N + 255) / 256, 256, 0, stream>>>(deg, dinv, N);

  int nb = (N + 255) / 256;
  if (use_csr) {
    k_scan1<<<nb, 256, 0, stream>>>(deg, exc, bsum, N);
    k_scan2<<<1, 256, 0, stream>>>(bsum, bbase, nb);
    k_scan3<<<(N + 256) / 256, 256, 0, stream>>>(exc, bbase, roff, cursor, N, E);
    k_fill<<<(E + 255) / 256, 256, 0, stream>>>(src, dst, cursor, csrc, E);
  }

  int aggBlocks = (N * 64 + 255) / 256;
  int n4 = N * HID / 4;
  if (use_csr) {
    for (int l = 0; l < 3; ++l) {
      const float* xin = (l == 0) ? x0 : OUT0;
      k_gemm_bf<<<512, 256, 0, stream>>>(xin, W[l], dinv, gbf, N);
      int mode = (l == 2) ? (g_in_ws ? 3 : 1) : 0;
      k_agg_bf<<<aggBlocks, 256, 0, stream>>>(gbf, roff, csrc, dinv, b[l], gm[l], bt[l],
                                              OUT0, OUT1, N, mode);
    }
    if (!g_in_ws)  // relu not fused (OUT1 still held g during last agg)
      k_relu<<<(n4 + 255) / 256, 256, 0, stream>>>(OUT0, OUT1, n4);
  } else {
    int scatBlocks = (E * 64 + 255) / 256;
    for (int l = 0; l < 3; ++l) {
      const float* xin = (l == 0) ? x0 : OUT0;
      int last = (l == 2);
      k_gemm<<<512, 256, 0, stream>>>(xin, W[l], dinv, OUT1, N);
      k_copy<<<(n4 + 255) / 256, 256, 0, stream>>>(OUT1, OUT0, n4);
      k_scatter<<<scatBlocks, 256, 0, stream>>>(OUT1, src, dst, OUT0, E);
      k_fin<<<aggBlocks, 256, 0, stream>>>(OUT0, dinv, b[l], gm[l], bt[l], N, last);
    }
    k_relu<<<(n4 + 255) / 256, 256, 0, stream>>>(OUT0, OUT1, n4);
  }
}

// Round 6
// 257.140 us; speedup vs baseline: 1.5551x; 1.2154x over previous
//
#include <hip/hip_runtime.h>
#include <cstddef>

#define HID 128
#define LN_EPS 1e-5f
#define GROWS 8

typedef unsigned int uint32;
typedef __attribute__((ext_vector_type(8))) short short8;
typedef __attribute__((ext_vector_type(4))) float f32x4;

__device__ __forceinline__ float wave_sum(float v) {
#pragma unroll
  for (int o = 32; o > 0; o >>= 1) v += __shfl_xor(v, o, 64);
  return v;
}

__device__ __forceinline__ uint32 bf16_rne(float x) {
  uint32 u = __float_as_uint(x);
  u += 0x7fffu + ((u >> 16) & 1u);
  return u >> 16;
}

// RNE-pack two fp32 into 2xbf16 (x -> low16, y -> high16)
__device__ __forceinline__ uint32 pack_bf2(float x, float y) {
  uint32 ux = __float_as_uint(x);
  uint32 uy = __float_as_uint(y);
  ux += 0x7fffu + ((ux >> 16) & 1u);
  uy += 0x7fffu + ((uy >> 16) & 1u);
  return (ux >> 16) | (uy & 0xffff0000u);
}

extern "C" __global__ void k_zero(int* __restrict__ p, int n) {
  int i = blockIdx.x * blockDim.x + threadIdx.x;
  if (i < n) p[i] = 0;
}

extern "C" __global__ void k_deg(const int* __restrict__ dst, int* __restrict__ deg, int E) {
  int i = blockIdx.x * blockDim.x + threadIdx.x;
  if (i < E) atomicAdd(&deg[dst[i]], 1);
}

extern "C" __global__ void k_dinv(const int* __restrict__ deg, float* __restrict__ dinv, int N) {
  int i = blockIdx.x * blockDim.x + threadIdx.x;
  if (i < N) dinv[i] = rsqrtf((float)deg[i] + 1.0f);
}

extern "C" __global__ void k_scan1(const int* __restrict__ in, int* __restrict__ exc,
                                   int* __restrict__ bsum, int n) {
  __shared__ int sh[256];
  int tid = threadIdx.x;
  int i = blockIdx.x * 256 + tid;
  int v = (i < n) ? in[i] : 0;
  sh[tid] = v;
  __syncthreads();
  for (int o = 1; o < 256; o <<= 1) {
    int t = (tid >= o) ? sh[tid - o] : 0;
    __syncthreads();
    sh[tid] += t;
    __syncthreads();
  }
  if (i < n) exc[i] = sh[tid] - v;
  if (tid == 255) bsum[blockIdx.x] = sh[255];
}

extern "C" __global__ void k_scan2(const int* __restrict__ bsum, int* __restrict__ bbase, int nb) {
  __shared__ int sh[256];
  int tid = threadIdx.x;
  int v = (tid < nb) ? bsum[tid] : 0;
  sh[tid] = v;
  __syncthreads();
  for (int o = 1; o < 256; o <<= 1) {
    int t = (tid >= o) ? sh[tid - o] : 0;
    __syncthreads();
    sh[tid] += t;
    __syncthreads();
  }
  if (tid < nb) bbase[tid] = sh[tid] - v;
}

extern "C" __global__ void k_scan3(const int* __restrict__ exc, const int* __restrict__ bbase,
                                   int* __restrict__ roff, int* __restrict__ cursor, int N, int E) {
  int i = blockIdx.x * blockDim.x + threadIdx.x;
  if (i < N) {
    int o = exc[i] + bbase[i >> 8];
    roff[i] = o;
    cursor[i] = o;
  } else if (i == N) {
    roff[N] = E;
  }
}

// XCD-partitioned CSR fill: block group (blockIdx&7) handles dst range
// [part*N/8,(part+1)*N/8) so all writes to a csrc cache line come from one XCD.
extern "C" __global__ void k_fill_p(const int* __restrict__ src, const int* __restrict__ dst,
                                    int* __restrict__ cursor, int* __restrict__ csrc,
                                    int E, int N) {
  int part = blockIdx.x & 7;
  int grp = blockIdx.x >> 3;
  int ngrp = gridDim.x >> 3;
  int lo = (int)((long long)N * part >> 3);
  int hi = (int)((long long)N * (part + 1) >> 3);
  for (int i = grp * blockDim.x + threadIdx.x; i < E; i += ngrp * blockDim.x) {
    int d = dst[i];
    if (d >= lo && d < hi) {
      int pos = atomicAdd(&cursor[d], 1);
      csrc[pos] = src[i];
    }
  }
}

// per-layer: wt[n*128+k] = bf16(W[k][n])
extern "C" __global__ void k_wt(const float* __restrict__ W, unsigned short* __restrict__ wt) {
  int i = blockIdx.x * 256 + threadIdx.x;
  if (i < HID * HID) {
    int n = i >> 7, k = i & 127;
    wt[i] = (unsigned short)bf16_rne(W[k * HID + n]);
  }
}

// MFMA GEMM: gb[r][c-pair] = bf16(dinv[r] * sum_k x[r][k]*W[k][c])
// block = 64 rows, 4 waves; wave wv -> rows [wv*16, wv*16+16), all 128 cols.
extern "C" __global__ __launch_bounds__(256) void k_gemm_mfma(
    const float* __restrict__ x, const unsigned short* __restrict__ wt,
    const float* __restrict__ dinv, uint32* __restrict__ gb, int N) {
  __shared__ unsigned short Wt[HID][136];  // Wt[n][k], +8 pad breaks bank conflicts
  __shared__ unsigned short Xs[64][136];   // Xs[r][k] bf16
  __shared__ float dv_s[64];
  int tid = threadIdx.x, lane = tid & 63, wv = tid >> 6;
  int r0 = blockIdx.x * 64;
  int nr = min(64, N - r0);
  // stage Wt (16384 bf16 = 2048 x short8)
  for (int i = tid; i < 2048; i += 256) {
    short8 v = *(const short8*)(wt + i * 8);
    int n = i >> 4, k0 = (i & 15) * 8;
    *(short8*)&Wt[n][k0] = v;
  }
  // stage Xs (convert fp32 -> bf16)
  {
    const float4* xs4 = (const float4*)(x + (size_t)r0 * HID);
    for (int i = tid; i < nr * 32; i += 256) {
      float4 v = xs4[i];
      int r = i >> 5, c = (i & 31) * 4;
      Xs[r][c + 0] = (unsigned short)bf16_rne(v.x);
      Xs[r][c + 1] = (unsigned short)bf16_rne(v.y);
      Xs[r][c + 2] = (unsigned short)bf16_rne(v.z);
      Xs[r][c + 3] = (unsigned short)bf16_rne(v.w);
    }
  }
  if (tid < 64) dv_s[tid] = (tid < nr) ? dinv[r0 + tid] : 0.f;
  __syncthreads();
  // A fragments: row = lane&15, k = (lane>>4)*8 + j
  short8 a[4];
  int arow = wv * 16 + (lane & 15);
  int kb = (lane >> 4) * 8;
#pragma unroll
  for (int q = 0; q < 4; ++q) a[q] = *(const short8*)&Xs[arow][q * 32 + kb];
  int bn = lane & 15;
#pragma unroll
  for (int c = 0; c < 8; ++c) {
    f32x4 acc = {0.f, 0.f, 0.f, 0.f};
    short8 b0 = *(const short8*)&Wt[c * 16 + bn][0 + kb];
    short8 b1 = *(const short8*)&Wt[c * 16 + bn][32 + kb];
    short8 b2 = *(const short8*)&Wt[c * 16 + bn][64 + kb];
    short8 b3 = *(const short8*)&Wt[c * 16 + bn][96 + kb];
    acc = __builtin_amdgcn_mfma_f32_16x16x32_bf16(a[0], b0, acc, 0, 0, 0);
    acc = __builtin_amdgcn_mfma_f32_16x16x32_bf16(a[1], b1, acc, 0, 0, 0);
    acc = __builtin_amdgcn_mfma_f32_16x16x32_bf16(a[2], b2, acc, 0, 0, 0);
    acc = __builtin_amdgcn_mfma_f32_16x16x32_bf16(a[3], b3, acc, 0, 0, 0);
    // D: col = lane&15, row = (lane>>4)*4 + reg (m89-verified)
#pragma unroll
    for (int reg = 0; reg < 4; ++reg) {
      float v = acc[reg];
      float p = __shfl_xor(v, 1, 64);  // partner col n^1
      int row = wv * 16 + (lane >> 4) * 4 + reg;
      if (!(lane & 1) && row < nr) {
        float dvv = dv_s[row];
        gb[(size_t)(r0 + row) * 64 + (c * 8 + (bn >> 1))] = pack_bf2(v * dvv, p * dvv);
      }
    }
  }
}

// vector-FMA GEMM fallback (used when ws can't hold wt)
extern "C" __global__ __launch_bounds__(256) void k_gemm_bf(
    const float* __restrict__ x, const float* __restrict__ W,
    const float* __restrict__ dinv, uint32* __restrict__ gb, int N) {
  __shared__ float Wl[HID * HID];
  __shared__ float xl[4][GROWS * HID];
  int tid = threadIdx.x;
#pragma unroll
  for (int i = 0; i < (HID * HID / 4) / 256; ++i)
    ((float4*)Wl)[tid + 256 * i] = ((const float4*)W)[tid + 256 * i];
  __syncthreads();
  int wid = tid >> 6, lane = tid & 63;
  float* xw = xl[wid];
  int nchunks = (N + GROWS - 1) / GROWS;
  int gw = blockIdx.x * 4 + wid;
  int nw = gridDim.x * 4;
  for (int chunk = gw; chunk < nchunks; chunk += nw) {
    int r0 = chunk * GROWS;
    int nr = min(GROWS, N - r0);
    const float4* xs = (const float4*)(x + (size_t)r0 * HID);
    float4* xd = (float4*)xw;
    if (nr == GROWS) {
#pragma unroll
      for (int i = 0; i < 4; ++i) xd[lane + 64 * i] = xs[lane + 64 * i];
    } else {
      for (int i = lane; i < nr * (HID / 4); i += 64) xd[i] = xs[i];
    }
    float2 acc[GROWS];
#pragma unroll
    for (int r = 0; r < GROWS; ++r) acc[r] = make_float2(0.f, 0.f);
    for (int k = 0; k < HID; k += 4) {
      float2 w0 = *(const float2*)&Wl[(k + 0) * HID + 2 * lane];
      float2 w1 = *(const float2*)&Wl[(k + 1) * HID + 2 * lane];
      float2 w2 = *(const float2*)&Wl[(k + 2) * HID + 2 * lane];
      float2 w3 = *(const float2*)&Wl[(k + 3) * HID + 2 * lane];
#pragma unroll
      for (int r = 0; r < GROWS; ++r) {
        float4 xq = *(const float4*)&xw[r * HID + k];
        acc[r].x = fmaf(xq.w, w3.x, fmaf(xq.z, w2.x, fmaf(xq.y, w1.x, fmaf(xq.x, w0.x, acc[r].x))));
        acc[r].y = fmaf(xq.w, w3.y, fmaf(xq.z, w2.y, fmaf(xq.y, w1.y, fmaf(xq.x, w0.y, acc[r].y))));
      }
    }
#pragma unroll
    for (int r = 0; r < GROWS; ++r) {
      if (r < nr) {
        float dv = dinv[r0 + r];
        gb[(size_t)(r0 + r) * 64 + lane] = pack_bf2(acc[r].x * dv, acc[r].y * dv);
      }
    }
  }
}

// h[v] = dinv[v]*(g[v] + sum g[src]) + b from bf16-packed g.
// mode 0: out0 = LN(relu(h)); mode 1: out0 = h; mode 3: out0 = h, out1 = relu(h)
extern "C" __global__ __launch_bounds__(256) void k_agg_bf(
    const uint32* __restrict__ gb, const int* __restrict__ roff, const int* __restrict__ csrc,
    const float* __restrict__ dinv, const float* __restrict__ bias,
    const float* __restrict__ gamma, const float* __restrict__ beta,
    float* __restrict__ out0, float* __restrict__ out1, int N, int mode) {
  int w = (int)((blockIdx.x * blockDim.x + threadIdx.x) >> 6);
  int lane = threadIdx.x & 63;
  if (w >= N) return;
  uint32 us = gb[(size_t)w * 64 + lane];
  int e = roff[w], e1 = roff[w + 1];
  float ax = __uint_as_float(us << 16);
  float ay = __uint_as_float(us & 0xffff0000u);
  for (; e < e1; e += 8) {
#pragma unroll
    for (int i = 0; i < 8; ++i) {
      int idx = e + i;
      int cl = (idx < e1) ? idx : (e1 - 1);
      int s = csrc[cl];
      uint32 u = gb[(size_t)s * 64 + lane];
      float m = (idx < e1) ? 1.f : 0.f;
      ax = fmaf(m, __uint_as_float(u << 16), ax);
      ay = fmaf(m, __uint_as_float(u & 0xffff0000u), ay);
    }
  }
  float dv = dinv[w];
  float2 bb = *(const float2*)(bias + 2 * lane);
  float hx = fmaf(ax, dv, bb.x);
  float hy = fmaf(ay, dv, bb.y);
  if (mode) {
    *(float2*)(out0 + (size_t)w * HID + 2 * lane) = make_float2(hx, hy);
    if (mode & 2)
      *(float2*)(out1 + (size_t)w * HID + 2 * lane) =
          make_float2(fmaxf(hx, 0.f), fmaxf(hy, 0.f));
  } else {
    float rx = fmaxf(hx, 0.f), ry = fmaxf(hy, 0.f);
    float mu = wave_sum(rx + ry) * (1.f / HID);
    float dx = rx - mu, dy = ry - mu;
    float var = wave_sum(dx * dx + dy * dy) * (1.f / HID);
    float sc = rsqrtf(var + LN_EPS);
    float2 ga = *(const float2*)(gamma + 2 * lane);
    float2 be = *(const float2*)(beta + 2 * lane);
    *(float2*)(out0 + (size_t)w * HID + 2 * lane) =
        make_float2(fmaf(dx * sc, ga.x, be.x), fmaf(dy * sc, ga.y, be.y));
  }
}

// ---- fp32 scatter fallback path (only used if workspace is tiny) ----
extern "C" __global__ __launch_bounds__(256) void k_gemm(
    const float* __restrict__ x, const float* __restrict__ W,
    const float* __restrict__ dinv, float* __restrict__ g, int N) {
  __shared__ float Wl[HID * HID];
  __shared__ float xl[4][GROWS * HID];
  int tid = threadIdx.x;
#pragma unroll
  for (int i = 0; i < (HID * HID / 4) / 256; ++i)
    ((float4*)Wl)[tid + 256 * i] = ((const float4*)W)[tid + 256 * i];
  __syncthreads();
  int wid = tid >> 6, lane = tid & 63;
  float* xw = xl[wid];
  int nchunks = (N + GROWS - 1) / GROWS;
  int gw = blockIdx.x * 4 + wid;
  int nw = gridDim.x * 4;
  for (int chunk = gw; chunk < nchunks; chunk += nw) {
    int r0 = chunk * GROWS;
    int nr = min(GROWS, N - r0);
    const float4* xs = (const float4*)(x + (size_t)r0 * HID);
    float4* xd = (float4*)xw;
    if (nr == GROWS) {
#pragma unroll
      for (int i = 0; i < 4; ++i) xd[lane + 64 * i] = xs[lane + 64 * i];
    } else {
      for (int i = lane; i < nr * (HID / 4); i += 64) xd[i] = xs[i];
    }
    float2 acc[GROWS];
#pragma unroll
    for (int r = 0; r < GROWS; ++r) acc[r] = make_float2(0.f, 0.f);
    for (int k = 0; k < HID; k += 4) {
      float2 w0 = *(const float2*)&Wl[(k + 0) * HID + 2 * lane];
      float2 w1 = *(const float2*)&Wl[(k + 1) * HID + 2 * lane];
      float2 w2 = *(const float2*)&Wl[(k + 2) * HID + 2 * lane];
      float2 w3 = *(const float2*)&Wl[(k + 3) * HID + 2 * lane];
#pragma unroll
      for (int r = 0; r < GROWS; ++r) {
        float4 xq = *(const float4*)&xw[r * HID + k];
        acc[r].x = fmaf(xq.w, w3.x, fmaf(xq.z, w2.x, fmaf(xq.y, w1.x, fmaf(xq.x, w0.x, acc[r].x))));
        acc[r].y = fmaf(xq.w, w3.y, fmaf(xq.z, w2.y, fmaf(xq.y, w1.y, fmaf(xq.x, w0.y, acc[r].y))));
      }
    }
#pragma unroll
    for (int r = 0; r < GROWS; ++r) {
      if (r < nr) {
        float dv = dinv[r0 + r];
        *(float2*)(g + (size_t)(r0 + r) * HID + 2 * lane) =
            make_float2(acc[r].x * dv, acc[r].y * dv);
      }
    }
  }
}

extern "C" __global__ void k_copy(const float* __restrict__ in, float* __restrict__ out, int n4) {
  int i = blockIdx.x * blockDim.x + threadIdx.x;
  if (i < n4) ((float4*)out)[i] = ((const float4*)in)[i];
}

extern "C" __global__ void k_scatter(const float* __restrict__ g, const int* __restrict__ src,
                                     const int* __restrict__ dst, float* __restrict__ acc, int E) {
  int e = (int)((blockIdx.x * blockDim.x + threadIdx.x) >> 6);
  int lane = threadIdx.x & 63;
  if (e >= E) return;
  int s = src[e], d = dst[e];
  float2 v = *(const float2*)(g + (size_t)s * HID + 2 * lane);
  float* p = acc + (size_t)d * HID + 2 * lane;
  atomicAdd(p, v.x);
  atomicAdd(p + 1, v.y);
}

extern "C" __global__ __launch_bounds__(256) void k_fin(
    float* __restrict__ a, const float* __restrict__ dinv, const float* __restrict__ bias,
    const float* __restrict__ gamma, const float* __restrict__ beta, int N, int last) {
  int w = (int)((blockIdx.x * blockDim.x + threadIdx.x) >> 6);
  int lane = threadIdx.x & 63;
  if (w >= N) return;
  float2 acc = *(const float2*)(a + (size_t)w * HID + 2 * lane);
  float dv = dinv[w];
  float2 bb = *(const float2*)(bias + 2 * lane);
  float hx = fmaf(acc.x, dv, bb.x);
  float hy = fmaf(acc.y, dv, bb.y);
  if (last) {
    *(float2*)(a + (size_t)w * HID + 2 * lane) = make_float2(hx, hy);
  } else {
    float rx = fmaxf(hx, 0.f), ry = fmaxf(hy, 0.f);
    float mu = wave_sum(rx + ry) * (1.f / HID);
    float dx = rx - mu, dy = ry - mu;
    float var = wave_sum(dx * dx + dy * dy) * (1.f / HID);
    float sc = rsqrtf(var + LN_EPS);
    float2 ga = *(const float2*)(gamma + 2 * lane);
    float2 be = *(const float2*)(beta + 2 * lane);
    *(float2*)(a + (size_t)w * HID + 2 * lane) =
        make_float2(fmaf(dx * sc, ga.x, be.x), fmaf(dy * sc, ga.y, be.y));
  }
}

extern "C" __global__ void k_relu(const float* __restrict__ in, float* __restrict__ out, int n4) {
  int i = blockIdx.x * blockDim.x + threadIdx.x;
  if (i < n4) {
    float4 v = ((const float4*)in)[i];
    v.x = fmaxf(v.x, 0.f);
    v.y = fmaxf(v.y, 0.f);
    v.z = fmaxf(v.z, 0.f);
    v.w = fmaxf(v.w, 0.f);
    ((float4*)out)[i] = v;
  }
}

extern "C" void kernel_launch(void* const* d_in, const int* in_sizes, int n_in,
                              void* d_out, int out_size, void* d_ws, size_t ws_size,
                              hipStream_t stream) {
  const float* x0 = (const float*)d_in[0];
  const int* ei = (const int*)d_in[1];
  int N = in_sizes[0] / HID;
  int E = in_sizes[1] / 2;

  const float* W[3];
  const float* b[3];
  const float* gm[3];
  const float* bt[3];
  if (n_in >= 14 && in_sizes[2] == HID * HID) {
    for (int l = 0; l < 3; ++l) {
      W[l] = (const float*)d_in[2 + l];
      b[l] = (const float*)d_in[5 + l];
      gm[l] = (const float*)d_in[8 + l];
      bt[l] = (const float*)d_in[11 + l];
    }
  } else if (n_in >= 6) {
    const float* Wc = (const float*)d_in[2];
    const float* bc = (const float*)d_in[3];
    const float* gc = (const float*)d_in[4];
    const float* tc = (const float*)d_in[5];
    for (int l = 0; l < 3; ++l) {
      W[l] = Wc + (size_t)l * HID * HID;
      b[l] = bc + (size_t)l * HID;
      gm[l] = gc + (size_t)l * HID;
      bt[l] = tc + (size_t)l * HID;
    }
  } else {
    return;
  }
  const int* src = ei;
  const int* dst = ei + E;

  float* OUT0 = (float*)d_out;
  float* OUT1 = OUT0 + (size_t)N * HID;

  // CSR-build transients live in OUT1 (dead until first gbf/last-agg use)
  int* deg = (int*)OUT1;
  int* exc = deg + N;
  int* cursor = exc + N;
  int* bsum = cursor + N;
  int* bbase = bsum + 256;

  auto align256 = [](size_t bytes) { return (bytes + 255) & ~(size_t)255; };
  size_t need_scatter = align256((size_t)N * 4);
  size_t need_csr = need_scatter + align256((size_t)(N + 1) * 4) + align256((size_t)E * 4);
  size_t need_wt = need_csr + align256((size_t)HID * HID * 2);
  size_t need_full = need_wt + (size_t)N * 256;  // + bf16 g (N*64 uints)
  if (ws_size < need_scatter) return;
  bool use_csr = (ws_size >= need_csr);
  bool use_mfma = (ws_size >= need_wt);
  bool g_in_ws = (ws_size >= need_full);

  char* wp = (char*)d_ws;
  float* dinv = (float*)wp;
  wp += align256((size_t)N * 4);
  int* roff = nullptr;
  int* csrc = nullptr;
  unsigned short* wtbf = nullptr;
  uint32* gbf = nullptr;
  if (use_csr) {
    roff = (int*)wp;
    wp += align256((size_t)(N + 1) * 4);
    csrc = (int*)wp;
    wp += align256((size_t)E * 4);
    if (use_mfma) {
      wtbf = (unsigned short*)wp;
      wp += align256((size_t)HID * HID * 2);
    }
    gbf = g_in_ws ? (uint32*)wp : (uint32*)OUT1;
  }

  k_zero<<<(N + 255) / 256, 256, 0, stream>>>(deg, N);
  k_deg<<<(E + 255) / 256, 256, 0, stream>>>(dst, deg, E);
  k_dinv<<<(N + 255) / 256, 256, 0, stream>>>(deg, dinv, N);

  int nb = (N + 255) / 256;
  if (use_csr) {
    k_scan1<<<nb, 256, 0, stream>>>(deg, exc, bsum, N);
    k_scan2<<<1, 256, 0, stream>>>(bsum, bbase, nb);
    k_scan3<<<(N + 256) / 256, 256, 0, stream>>>(exc, bbase, roff, cursor, N, E);
    k_fill_p<<<2048, 256, 0, stream>>>(src, dst, cursor, csrc, E, N);
  }

  int aggBlocks = (N * 64 + 255) / 256;
  int n4 = N * HID / 4;
  if (use_csr) {
    for (int l = 0; l < 3; ++l) {
      const float* xin = (l == 0) ? x0 : OUT0;
      if (use_mfma) {
        k_wt<<<(HID * HID + 255) / 256, 256, 0, stream>>>(W[l], wtbf);
        k_gemm_mfma<<<(N + 63) / 64, 256, 0, stream>>>(xin, wtbf, dinv, gbf, N);
      } else {
        k_gemm_bf<<<512, 256, 0, stream>>>(xin, W[l], dinv, gbf, N);
      }
      int mode = (l == 2) ? (g_in_ws ? 3 : 1) : 0;
      k_agg_bf<<<aggBlocks, 256, 0, stream>>>(gbf, roff, csrc, dinv, b[l], gm[l], bt[l],
                                              OUT0, OUT1, N, mode);
    }
    if (!g_in_ws)
      k_relu<<<(n4 + 255) / 256, 256, 0, stream>>>(OUT0, OUT1, n4);
  } else {
    int scatBlocks = (E * 64 + 255) / 256;
    for (int l = 0; l < 3; ++l) {
      const float* xin = (l == 0) ? x0 : OUT0;
      int last = (l == 2);
      k_gemm<<<512, 256, 0, stream>>>(xin, W[l], dinv, OUT1, N);
      k_copy<<<(n4 + 255) / 256, 256, 0, stream>>>(OUT1, OUT0, n4);
      k_scatter<<<scatBlocks, 256, 0, stream>>>(OUT1, src, dst, OUT0, E);
      k_fin<<<aggBlocks, 256, 0, stream>>>(OUT0, dinv, b[l], gm[l], bt[l], N, last);
    }
    k_relu<<<(n4 + 255) / 256, 256, 0, stream>>>(OUT0, OUT1, n4);
  }
}